// Round 4
// baseline (349.117 us; speedup 1.0000x reference)
//
#include <hip/hip_runtime.h>
#include <math.h>

#define NN 100000      // nodes
#define CD 32          // classes / hidden
#define NPB 4          // nodes (waves) per block in fused gather+dense kernels

#define B1N ((NN + 255) >> 8)   // 391 coarse buckets (256 nodes each)
#define EPB_A 2048              // edges per partition block (256 thr x 8)

typedef unsigned int   uint32;
typedef unsigned short ushort16;

// fp32 -> bf16 round-to-nearest-even
__device__ __forceinline__ ushort16 f2b(float f) {
    uint32 u = __float_as_uint(f);
    u = (u + 0x7FFFu + ((u >> 16) & 1u)) >> 16;
    return (ushort16)u;
}
// packed bf16 pair -> two fp32 (exact)
__device__ __forceinline__ float b2f_lo(uint32 u) { return __uint_as_float(u << 16); }
__device__ __forceinline__ float b2f_hi(uint32 u) { return __uint_as_float(u & 0xFFFF0000u); }

// Inline is64 detection (replaces the detect_idx64 dispatch): every wave
// checks the first 512 values interpreted as i64; L2-hot after first block.
__device__ __forceinline__ int edge_is64(const void* edge) {
    const long long* p = (const long long*)edge;
    int lane = threadIdx.x & 63;
    int bad = 0;
    for (int i = lane; i < 512; i += 64) {
        long long v = p[i];
        if (v < 0 || v >= NN) bad = 1;
    }
    unsigned long long anybad = __ballot(bad);
    return (anybad == 0ULL) ? 1 : 0;
}

__device__ __forceinline__ int load_idx(const void* edge, int i, int is64) {
    if (is64) return (int)((const long long*)edge)[i];
    return ((const int*)edge)[i];
}

// ---------------------------------------------------------------------------
// x (fp32, NN x 50) -> packed bf16 rows, stride 32 uints (128 B, cacheline-
// aligned; uints 25..31 zero pad). R16-proven: aligned pow-2 rows = exactly
// one line per random row gather + 32-bit saddr addressing.
__global__ void cvt_x_kernel(const float* __restrict__ x, uint32* __restrict__ xb) {
    const int t = blockIdx.x * blockDim.x + threadIdx.x;
    if (t >= NN * 32) return;
    const int n = t >> 5;
    const int c = t & 31;
    if (c >= 25) { xb[t] = 0; return; }
    float2 v = *(const float2*)&x[n * 50 + 2 * c];
    xb[t] = (uint32)f2b(v.x) | ((uint32)f2b(v.y) << 16);
}

// ---------------------------------------------------------------------------
// CSR build, atomic-free at device scope (R15-proven). All atomics in LDS.

__global__ __launch_bounds__(256) void hist_kernel(const void* edge, int E,
                                                   int* __restrict__ hist) {
    __shared__ int lh[B1N];
    const int is64 = edge_is64(edge);
    const int t = threadIdx.x;
    for (int b = t; b < B1N; b += 256) lh[b] = 0;
    __syncthreads();
    const int e0 = blockIdx.x * EPB_A + t;
#pragma unroll
    for (int k = 0; k < 8; ++k) {
        int e = e0 + k * 256;
        if (e < E) {
            int d = load_idx(edge, E + e, is64);
            atomicAdd(&lh[d >> 8], 1);
        }
    }
    __syncthreads();
    int* gh = hist + (size_t)blockIdx.x * B1N;
    for (int b = t; b < B1N; b += 256) gh[b] = lh[b];
}

// One block per bin: exclusive scan of hist[b][bin] over blocks b (in place),
// bin total to binTotal[bin]. Supports nblk <= 1024 (4 per thread).
__global__ __launch_bounds__(256) void scanA_kernel(int* __restrict__ hist,
                                                    int nblk,
                                                    int* __restrict__ binTotal) {
    __shared__ int ts[256];
    const int bin = blockIdx.x;
    const int t = threadIdx.x;
    const int base = t * 4;
    int v0 = (base + 0 < nblk) ? hist[(size_t)(base + 0) * B1N + bin] : 0;
    int v1 = (base + 1 < nblk) ? hist[(size_t)(base + 1) * B1N + bin] : 0;
    int v2 = (base + 2 < nblk) ? hist[(size_t)(base + 2) * B1N + bin] : 0;
    int v3 = (base + 3 < nblk) ? hist[(size_t)(base + 3) * B1N + bin] : 0;
    const int s = v0 + v1 + v2 + v3;
    ts[t] = s;
    __syncthreads();
    for (int off = 1; off < 256; off <<= 1) {
        int u = (t >= off) ? ts[t - off] : 0;
        __syncthreads();
        ts[t] += u;
        __syncthreads();
    }
    int e = ts[t] - s;
    if (base + 0 < nblk) { hist[(size_t)(base + 0) * B1N + bin] = e; e += v0; }
    if (base + 1 < nblk) { hist[(size_t)(base + 1) * B1N + bin] = e; e += v1; }
    if (base + 2 < nblk) { hist[(size_t)(base + 2) * B1N + bin] = e; e += v2; }
    if (base + 3 < nblk) { hist[(size_t)(base + 3) * B1N + bin] = e; e += v3; }
    if (t == 255) binTotal[bin] = ts[255];
}

// In-block exclusive scan of binTotal[B1N] -> lbase[B1N+1] (LDS).
__device__ __forceinline__ void scan_bins_lds(const int* __restrict__ binTotal,
                                              int* ts, int* lbase) {
    const int t = threadIdx.x;
    const int base = t * 2;
    const int v0 = (base + 0 < B1N) ? binTotal[base + 0] : 0;
    const int v1 = (base + 1 < B1N) ? binTotal[base + 1] : 0;
    const int s = v0 + v1;
    ts[t] = s;
    __syncthreads();
    for (int off = 1; off < 256; off <<= 1) {
        int u = (t >= off) ? ts[t - off] : 0;
        __syncthreads();
        ts[t] += u;
        __syncthreads();
    }
    const int e = ts[t] - s;
    if (base + 0 < B1N) lbase[base + 0] = e;
    if (base + 1 < B1N) lbase[base + 1] = e + v0;
    if (t == 255) lbase[B1N] = ts[255];     // == E
    __syncthreads();
}

__global__ __launch_bounds__(256) void scatter_kernel(const void* edge, int E,
                                                      const int* __restrict__ hist,
                                                      const int* __restrict__ binTotal,
                                                      uint32* __restrict__ bucketed) {
    __shared__ int ts[256];
    __shared__ int lbase[B1N + 1];
    __shared__ int cur[B1N];
    const int is64 = edge_is64(edge);
    const int t = threadIdx.x;
    scan_bins_lds(binTotal, ts, lbase);
    const int* gh = hist + (size_t)blockIdx.x * B1N;
    for (int b = t; b < B1N; b += 256) cur[b] = lbase[b] + gh[b];
    __syncthreads();
    const int e0 = blockIdx.x * EPB_A + t;
#pragma unroll
    for (int k = 0; k < 8; ++k) {
        int e = e0 + k * 256;
        if (e < E) {
            int s = load_idx(edge, e, is64);
            int d = load_idx(edge, E + e, is64);
            int pos = atomicAdd(&cur[d >> 8], 1);   // LDS atomic
            bucketed[pos] = (uint32)s | ((uint32)(d & 255) << 17);
        }
    }
}

__global__ __launch_bounds__(256) void bucket_kernel(const uint32* __restrict__ bucketed,
                                                     const int* __restrict__ binTotal,
                                                     int* __restrict__ offsets,
                                                     int* __restrict__ csr_src) {
    __shared__ int ts[256];
    __shared__ int lbase[B1N + 1];
    __shared__ int h[256];
    __shared__ int sc[256];
    __shared__ int cur[256];
    const int bkt = blockIdx.x;
    const int t = threadIdx.x;
    scan_bins_lds(binTotal, ts, lbase);
    const int start = lbase[bkt];
    const int end   = lbase[bkt + 1];
    h[t] = 0;
    __syncthreads();
    for (int i = start + t; i < end; i += 256)
        atomicAdd(&h[bucketed[i] >> 17], 1);        // LDS atomic
    __syncthreads();
    const int v = h[t];
    sc[t] = v;
    __syncthreads();
    for (int off = 1; off < 256; off <<= 1) {
        int u = (t >= off) ? sc[t - off] : 0;
        __syncthreads();
        sc[t] += u;
        __syncthreads();
    }
    const int excl = sc[t] - v;
    const int node = bkt * 256 + t;
    if (node < NN) offsets[node] = start + excl;    // coalesced
    cur[t] = start + excl;
    __syncthreads();
    for (int i = start + t; i < end; i += 256) {
        uint32 p = bucketed[i];
        int pos = atomicAdd(&cur[p >> 17], 1);      // LDS atomic
        csr_src[pos] = (int)(p & 0x1FFFFu);         // L2-local scatter (16KB window)
    }
    if (bkt == B1N - 1 && t == 0) offsets[NN] = end;   // == E
}

// ---------------------------------------------------------------------------
// Fused gather-max + dense (R17/R18). R18: the first fused dense_phase used
// ONE accumulator -> 50-deep serial FMA chain (~200 cyc/node, +30 us on
// fused50). Fix: 4 independent accumulators (chain /4) + float4 LDS broadcast
// reads (ds_read_b128, 50 -> 13 LDS ops); the 4 W loads per step are
// independent so the L1 pipe overlaps.

template <int DIN, int MODE>
__device__ __forceinline__ void dense_phase(const float* lds_agg, const float* lds_x,
                                            const float* __restrict__ Wl,
                                            const float* __restrict__ bl,
                                            const float* __restrict__ Wr,
                                            int n, void* __restrict__ out_v, int lane) {
    const int l = lane & 31;
    const int p = lane >> 5;
    const float* W   = p ? Wr : Wl;
    const float* src = p ? lds_x : lds_agg;
    float a0 = 0.0f, a1 = 0.0f, a2 = 0.0f, a3 = 0.0f;
#pragma unroll
    for (int c = 0; c < (DIN & ~3); c += 4) {
        float4 v = *(const float4*)&src[c];
        a0 += v.x * W[(c + 0) * CD + l];
        a1 += v.y * W[(c + 1) * CD + l];
        a2 += v.z * W[(c + 2) * CD + l];
        a3 += v.w * W[(c + 3) * CD + l];
    }
    if (DIN & 3) {   // DIN=50: 2 tail channels
        float2 v = *(const float2*)&src[DIN & ~3];
        a0 += v.x * W[(DIN - 2) * CD + l];
        a1 += v.y * W[(DIN - 1) * CD + l];
    }
    float acc = (a0 + a1) + (a2 + a3);
    acc += __shfl_xor(acc, 32);      // combine Wl-term and Wr-term halves
    acc += bl[l];
    if (MODE == 0) {
        float r = fmaxf(acc, 0.0f);
        float a = __shfl(r, 2 * l);          // out[2t]   (valid reads for l<16)
        float b = __shfl(r, 2 * l + 1);      // out[2t+1]
        if (lane < 16) {
            ((uint32*)out_v)[(size_t)n * 16 + lane] =
                (uint32)f2b(a) | ((uint32)f2b(b) << 16);
        }
    } else {
        float m = acc;
#pragma unroll
        for (int o = 1; o < 32; o <<= 1) m = fmaxf(m, __shfl_xor(m, o));
        float e = expf(acc - m);
        float s = e;
#pragma unroll
        for (int o = 1; o < 32; o <<= 1) s += __shfl_xor(s, o);
        const float lse = m + logf(s);
        if (p == 0) ((float*)out_v)[(size_t)n * CD + l] = acc - lse;
    }
}

// Layer 1: hb = xb (stride 32 uints, 128-B rows), DIN=50.
__global__ void fused50_kernel(const uint32* __restrict__ hb,
                               const int* __restrict__ offsets,
                               const int* __restrict__ csr_src,
                               const float* __restrict__ Wl,
                               const float* __restrict__ bl,
                               const float* __restrict__ Wr,
                               void* __restrict__ out_v) {
    __shared__ float lds_buf[NPB][2][64];
    const int tid  = threadIdx.x;
    const int g    = tid >> 6;
    const int lane = tid & 63;
    const int p    = lane >> 5;
    const int j    = lane & 31;
    const int n    = blockIdx.x * NPB + g;
    if (n >= NN) return;

    float* lds_agg = lds_buf[g][0];
    float* lds_x   = lds_buf[g][1];

    const float NEG = -INFINITY;
    const int beg = offsets[n];
    const int end = offsets[n + 1];
    const char* hbase = (const char*)hb;
    const uint32 joff = (uint32)(j << 2);

    // p=1 half loads the node's own row while p=0 will write agg later.
    if (p == 1 && j < 25) {
        uint32 u = hb[(size_t)n * 32 + j];
        lds_x[2 * j]     = b2f_lo(u);
        lds_x[2 * j + 1] = b2f_hi(u);
    }

    float lo_[8], hi_[8];
#pragma unroll
    for (int k = 0; k < 8; ++k) { lo_[k] = NEG; hi_[k] = NEG; }
    int i = beg + p;
    for (; i + 14 < end; i += 16) {
        int s[8];
#pragma unroll
        for (int k = 0; k < 8; ++k) s[k] = csr_src[i + 2 * k];
#pragma unroll
        for (int k = 0; k < 8; ++k) {
            uint32 u = *(const uint32*)(hbase + ((((uint32)s[k]) << 7) | joff));
            lo_[k] = fmaxf(lo_[k], b2f_lo(u));
            hi_[k] = fmaxf(hi_[k], b2f_hi(u));
        }
    }
#pragma unroll
    for (int k = 0; k < 7; ++k) {
        if (i + 2 * k < end) {
            uint32 u = *(const uint32*)(hbase + ((((uint32)csr_src[i + 2 * k]) << 7) | joff));
            lo_[k] = fmaxf(lo_[k], b2f_lo(u));
            hi_[k] = fmaxf(hi_[k], b2f_hi(u));
        }
    }
#pragma unroll
    for (int off2 = 4; off2 > 0; off2 >>= 1)
#pragma unroll
        for (int k = 0; k < off2; ++k) {
            lo_[k] = fmaxf(lo_[k], lo_[k + off2]);
            hi_[k] = fmaxf(hi_[k], hi_[k + off2]);
        }
    float lo = lo_[0], hi = hi_[0];
    lo = fmaxf(lo, __shfl_xor(lo, 32));
    hi = fmaxf(hi, __shfl_xor(hi, 32));
    lo = (lo == NEG) ? 0.0f : lo;
    hi = (hi == NEG) ? 0.0f : hi;
    if (p == 0 && j < 25) {
        lds_agg[2 * j]     = lo;
        lds_agg[2 * j + 1] = hi;
    }
    // Wave-private LDS: compiler inserts lgkmcnt waits; no barrier needed.
    dense_phase<50, 0>(lds_agg, lds_x, Wl, bl, Wr, n, out_v, lane);
}

// Layers 2/3: hb = h (stride 16 uints, 64-B rows), DIN=32.
template <int MODE>
__global__ void fused32_kernel(const uint32* __restrict__ hb,
                               const int* __restrict__ offsets,
                               const int* __restrict__ csr_src,
                               const float* __restrict__ Wl,
                               const float* __restrict__ bl,
                               const float* __restrict__ Wr,
                               void* __restrict__ out_v) {
    __shared__ float lds_buf[NPB][2][64];
    const int tid  = threadIdx.x;
    const int g    = tid >> 6;
    const int lane = tid & 63;
    const int e    = lane >> 4;        // edge slot 0..3
    const int c    = lane & 15;        // uint chunk
    const int n    = blockIdx.x * NPB + g;
    if (n >= NN) return;

    float* lds_agg = lds_buf[g][0];
    float* lds_x   = lds_buf[g][1];

    const float NEG = -INFINITY;
    const int beg = offsets[n];
    const int end = offsets[n + 1];
    const char* hbase = (const char*)hb;
    const uint32 coff = (uint32)(c << 2);

    // lanes 16..31 load the node's own row in parallel with the gather.
    if (e == 1) {
        uint32 u = hb[(size_t)n * 16 + c];
        lds_x[2 * c]     = b2f_lo(u);
        lds_x[2 * c + 1] = b2f_hi(u);
    }

    float l0 = NEG, h0 = NEG, l1 = NEG, h1 = NEG;
    float l2 = NEG, h2 = NEG, l3 = NEG, h3 = NEG;
    int i = beg + e;
    for (; i + 12 < end; i += 16) {    // 16 edges per iter, all lanes active
        int s0 = csr_src[i];
        int s1 = csr_src[i + 4];
        int s2 = csr_src[i + 8];
        int s3 = csr_src[i + 12];
        uint32 u0 = *(const uint32*)(hbase + ((((uint32)s0) << 6) | coff));
        uint32 u1 = *(const uint32*)(hbase + ((((uint32)s1) << 6) | coff));
        uint32 u2 = *(const uint32*)(hbase + ((((uint32)s2) << 6) | coff));
        uint32 u3 = *(const uint32*)(hbase + ((((uint32)s3) << 6) | coff));
        l0 = fmaxf(l0, b2f_lo(u0)); h0 = fmaxf(h0, b2f_hi(u0));
        l1 = fmaxf(l1, b2f_lo(u1)); h1 = fmaxf(h1, b2f_hi(u1));
        l2 = fmaxf(l2, b2f_lo(u2)); h2 = fmaxf(h2, b2f_hi(u2));
        l3 = fmaxf(l3, b2f_lo(u3)); h3 = fmaxf(h3, b2f_hi(u3));
    }
    if (i < end) {
        uint32 u = *(const uint32*)(hbase + ((((uint32)csr_src[i]) << 6) | coff));
        l0 = fmaxf(l0, b2f_lo(u)); h0 = fmaxf(h0, b2f_hi(u));
    }
    if (i + 4 < end) {
        uint32 u = *(const uint32*)(hbase + ((((uint32)csr_src[i + 4]) << 6) | coff));
        l1 = fmaxf(l1, b2f_lo(u)); h1 = fmaxf(h1, b2f_hi(u));
    }
    if (i + 8 < end) {
        uint32 u = *(const uint32*)(hbase + ((((uint32)csr_src[i + 8]) << 6) | coff));
        l2 = fmaxf(l2, b2f_lo(u)); h2 = fmaxf(h2, b2f_hi(u));
    }
    float lo = fmaxf(fmaxf(l0, l1), fmaxf(l2, l3));
    float hi = fmaxf(fmaxf(h0, h1), fmaxf(h2, h3));
    lo = fmaxf(lo, __shfl_xor(lo, 16));   // combine edge slots 0<->1, 2<->3
    hi = fmaxf(hi, __shfl_xor(hi, 16));
    lo = fmaxf(lo, __shfl_xor(lo, 32));   // combine pairs
    hi = fmaxf(hi, __shfl_xor(hi, 32));
    lo = (lo == NEG) ? 0.0f : lo;
    hi = (hi == NEG) ? 0.0f : hi;
    if (lane < 16) {
        lds_agg[2 * c]     = lo;
        lds_agg[2 * c + 1] = hi;
    }
    dense_phase<32, MODE>(lds_agg, lds_x, Wl, bl, Wr, n, out_v, lane);
}

// ---------------------------------------------------------------------------
extern "C" void kernel_launch(void* const* d_in, const int* in_sizes, int n_in,
                              void* d_out, int out_size, void* d_ws, size_t ws_size,
                              hipStream_t stream) {
    const float* x    = (const float*)d_in[0];
    const void*  edge = d_in[1];
    const float* Wl1 = (const float*)d_in[2];
    const float* bl1 = (const float*)d_in[3];
    const float* Wr1 = (const float*)d_in[4];
    const float* Wl2 = (const float*)d_in[5];
    const float* bl2 = (const float*)d_in[6];
    const float* Wr2 = (const float*)d_in[7];
    const float* Wl3 = (const float*)d_in[8];
    const float* bl3 = (const float*)d_in[9];
    const float* Wr3 = (const float*)d_in[10];

    const int E = in_sizes[1] / 2;

    // Workspace carve-up (256B aligned), ~26 MB. bucketed + hist live in
    // d_out (dead before the final fused32<2> writes there); h2b reuses xb
    // (dead after fused-L1).
    char* ws = (char*)d_ws;
    size_t off = 0;
    auto carve = [&](size_t bytes) {
        void* p = ws + off;
        off = (off + bytes + 255) & ~(size_t)255;
        return p;
    };
    int*    offsets   = (int*)   carve((size_t)(NN + 1) * 4);
    int*    binTotal  = (int*)   carve((size_t)B1N * 4);
    int*    csr_src   = (int*)   carve((size_t)E * 4);
    uint32* xb        = (uint32*)carve((size_t)NN * 32 * 4);  // 12.8 MB
    uint32* h1b       = (uint32*)carve((size_t)NN * 16 * 4);  // 6.4 MB
    (void)ws_size; (void)n_in; (void)out_size;

    uint32* bucketed = (uint32*)d_out;     // 6.4 MB, dead before final layer
    int*    hist     = (int*)((char*)d_out + (((size_t)E * 4 + 255) & ~(size_t)255));
    uint32* h2b  = xb;                     // xb dead after fused-L1

    cvt_x_kernel<<<(NN * 32 + 255) / 256, 256, 0, stream>>>(x, xb);

    // CSR build, LDS-atomic bucketing (no device-scope atomics, no memset).
    const int nblkA = (E + EPB_A - 1) / EPB_A;     // 782 for E=1.6M
    hist_kernel<<<nblkA, 256, 0, stream>>>(edge, E, hist);
    scanA_kernel<<<B1N, 256, 0, stream>>>(hist, nblkA, binTotal);
    scatter_kernel<<<nblkA, 256, 0, stream>>>(edge, E, hist, binTotal, bucketed);
    bucket_kernel<<<B1N, 256, 0, stream>>>(bucketed, binTotal, offsets, csr_src);

    const int gb = (NN + NPB - 1) / NPB;      // wave per node

    // Layer 1: 50 -> 32, relu (fused gather+dense)
    fused50_kernel<<<gb, 256, 0, stream>>>(xb, offsets, csr_src, Wl1, bl1, Wr1, h1b);
    // Layer 2: 32 -> 32, relu
    fused32_kernel<0><<<gb, 256, 0, stream>>>(h1b, offsets, csr_src, Wl2, bl2, Wr2, h2b);
    // Layer 3: 32 -> 32, log_softmax -> fp32 d_out
    fused32_kernel<2><<<gb, 256, 0, stream>>>(h2b, offsets, csr_src, Wl3, bl3, Wr3, d_out);
}

// Round 6
// 316.238 us; speedup vs baseline: 1.1040x; 1.1040x over previous
//
#include <hip/hip_runtime.h>
#include <math.h>

#define NN 100000      // nodes
#define CD 32          // classes / hidden
#define NPB 4          // nodes (waves) per block in gather kernels

#define B1N ((NN + 255) >> 8)   // 391 coarse buckets (256 nodes each)
#define EPB_A 2048              // edges per partition block (256 thr x 8)

typedef unsigned int   uint32;
typedef unsigned short ushort16;

// fp32 -> bf16 round-to-nearest-even
__device__ __forceinline__ ushort16 f2b(float f) {
    uint32 u = __float_as_uint(f);
    u = (u + 0x7FFFu + ((u >> 16) & 1u)) >> 16;
    return (ushort16)u;
}
// packed bf16 pair -> two fp32 (exact)
__device__ __forceinline__ float b2f_lo(uint32 u) { return __uint_as_float(u << 16); }
__device__ __forceinline__ float b2f_hi(uint32 u) { return __uint_as_float(u & 0xFFFF0000u); }

// Inline is64 detection (R17): every wave checks the first 512 values
// interpreted as i64; L2-hot after first block.
__device__ __forceinline__ int edge_is64(const void* edge) {
    const long long* p = (const long long*)edge;
    int lane = threadIdx.x & 63;
    int bad = 0;
    for (int i = lane; i < 512; i += 64) {
        long long v = p[i];
        if (v < 0 || v >= NN) bad = 1;
    }
    unsigned long long anybad = __ballot(bad);
    return (anybad == 0ULL) ? 1 : 0;
}

__device__ __forceinline__ int load_idx(const void* edge, int i, int is64) {
    if (is64) return (int)((const long long*)edge)[i];
    return ((const int*)edge)[i];
}

// ---------------------------------------------------------------------------
// x (fp32, NN x 50) -> packed bf16 rows, stride 32 uints (128 B, cacheline-
// aligned; uints 25..31 zero pad). R16-proven: aligned pow-2 rows = exactly
// one line per random row gather + 32-bit saddr addressing.
__global__ void cvt_x_kernel(const float* __restrict__ x, uint32* __restrict__ xb) {
    const int t = blockIdx.x * blockDim.x + threadIdx.x;
    if (t >= NN * 32) return;
    const int n = t >> 5;
    const int c = t & 31;
    if (c >= 25) { xb[t] = 0; return; }
    float2 v = *(const float2*)&x[n * 50 + 2 * c];
    xb[t] = (uint32)f2b(v.x) | ((uint32)f2b(v.y) << 16);
}

// ---------------------------------------------------------------------------
// CSR build, atomic-free at device scope (R15-proven). All atomics in LDS.

__global__ __launch_bounds__(256) void hist_kernel(const void* edge, int E,
                                                   int* __restrict__ hist) {
    __shared__ int lh[B1N];
    const int is64 = edge_is64(edge);
    const int t = threadIdx.x;
    for (int b = t; b < B1N; b += 256) lh[b] = 0;
    __syncthreads();
    const int e0 = blockIdx.x * EPB_A + t;
#pragma unroll
    for (int k = 0; k < 8; ++k) {
        int e = e0 + k * 256;
        if (e < E) {
            int d = load_idx(edge, E + e, is64);
            atomicAdd(&lh[d >> 8], 1);
        }
    }
    __syncthreads();
    int* gh = hist + (size_t)blockIdx.x * B1N;
    for (int b = t; b < B1N; b += 256) gh[b] = lh[b];
}

// One block per bin: exclusive scan of hist[b][bin] over blocks b (in place),
// bin total to binTotal[bin]. Supports nblk <= 1024 (4 per thread).
__global__ __launch_bounds__(256) void scanA_kernel(int* __restrict__ hist,
                                                    int nblk,
                                                    int* __restrict__ binTotal) {
    __shared__ int ts[256];
    const int bin = blockIdx.x;
    const int t = threadIdx.x;
    const int base = t * 4;
    int v0 = (base + 0 < nblk) ? hist[(size_t)(base + 0) * B1N + bin] : 0;
    int v1 = (base + 1 < nblk) ? hist[(size_t)(base + 1) * B1N + bin] : 0;
    int v2 = (base + 2 < nblk) ? hist[(size_t)(base + 2) * B1N + bin] : 0;
    int v3 = (base + 3 < nblk) ? hist[(size_t)(base + 3) * B1N + bin] : 0;
    const int s = v0 + v1 + v2 + v3;
    ts[t] = s;
    __syncthreads();
    for (int off = 1; off < 256; off <<= 1) {
        int u = (t >= off) ? ts[t - off] : 0;
        __syncthreads();
        ts[t] += u;
        __syncthreads();
    }
    int e = ts[t] - s;
    if (base + 0 < nblk) { hist[(size_t)(base + 0) * B1N + bin] = e; e += v0; }
    if (base + 1 < nblk) { hist[(size_t)(base + 1) * B1N + bin] = e; e += v1; }
    if (base + 2 < nblk) { hist[(size_t)(base + 2) * B1N + bin] = e; e += v2; }
    if (base + 3 < nblk) { hist[(size_t)(base + 3) * B1N + bin] = e; e += v3; }
    if (t == 255) binTotal[bin] = ts[255];
}

// In-block exclusive scan of binTotal[B1N] -> lbase[B1N+1] (LDS).
__device__ __forceinline__ void scan_bins_lds(const int* __restrict__ binTotal,
                                              int* ts, int* lbase) {
    const int t = threadIdx.x;
    const int base = t * 2;
    const int v0 = (base + 0 < B1N) ? binTotal[base + 0] : 0;
    const int v1 = (base + 1 < B1N) ? binTotal[base + 1] : 0;
    const int s = v0 + v1;
    ts[t] = s;
    __syncthreads();
    for (int off = 1; off < 256; off <<= 1) {
        int u = (t >= off) ? ts[t - off] : 0;
        __syncthreads();
        ts[t] += u;
        __syncthreads();
    }
    const int e = ts[t] - s;
    if (base + 0 < B1N) lbase[base + 0] = e;
    if (base + 1 < B1N) lbase[base + 1] = e + v0;
    if (t == 255) lbase[B1N] = ts[255];     // == E
    __syncthreads();
}

__global__ __launch_bounds__(256) void scatter_kernel(const void* edge, int E,
                                                      const int* __restrict__ hist,
                                                      const int* __restrict__ binTotal,
                                                      uint32* __restrict__ bucketed) {
    __shared__ int ts[256];
    __shared__ int lbase[B1N + 1];
    __shared__ int cur[B1N];
    const int is64 = edge_is64(edge);
    const int t = threadIdx.x;
    scan_bins_lds(binTotal, ts, lbase);
    const int* gh = hist + (size_t)blockIdx.x * B1N;
    for (int b = t; b < B1N; b += 256) cur[b] = lbase[b] + gh[b];
    __syncthreads();
    const int e0 = blockIdx.x * EPB_A + t;
#pragma unroll
    for (int k = 0; k < 8; ++k) {
        int e = e0 + k * 256;
        if (e < E) {
            int s = load_idx(edge, e, is64);
            int d = load_idx(edge, E + e, is64);
            int pos = atomicAdd(&cur[d >> 8], 1);   // LDS atomic
            bucketed[pos] = (uint32)s | ((uint32)(d & 255) << 17);
        }
    }
}

__global__ __launch_bounds__(256) void bucket_kernel(const uint32* __restrict__ bucketed,
                                                     const int* __restrict__ binTotal,
                                                     int* __restrict__ offsets,
                                                     int* __restrict__ csr_src) {
    __shared__ int ts[256];
    __shared__ int lbase[B1N + 1];
    __shared__ int h[256];
    __shared__ int sc[256];
    __shared__ int cur[256];
    const int bkt = blockIdx.x;
    const int t = threadIdx.x;
    scan_bins_lds(binTotal, ts, lbase);
    const int start = lbase[bkt];
    const int end   = lbase[bkt + 1];
    h[t] = 0;
    __syncthreads();
    for (int i = start + t; i < end; i += 256)
        atomicAdd(&h[bucketed[i] >> 17], 1);        // LDS atomic
    __syncthreads();
    const int v = h[t];
    sc[t] = v;
    __syncthreads();
    for (int off = 1; off < 256; off <<= 1) {
        int u = (t >= off) ? sc[t - off] : 0;
        __syncthreads();
        sc[t] += u;
        __syncthreads();
    }
    const int excl = sc[t] - v;
    const int node = bkt * 256 + t;
    if (node < NN) offsets[node] = start + excl;    // coalesced
    cur[t] = start + excl;
    __syncthreads();
    for (int i = start + t; i < end; i += 256) {
        uint32 p = bucketed[i];
        int pos = atomicAdd(&cur[p >> 17], 1);      // LDS atomic
        csr_src[pos] = (int)(p & 0x1FFFFu);         // L2-local scatter (16KB window)
    }
    if (bkt == B1N - 1 && t == 0) offsets[NN] = end;   // == E
}

// ---------------------------------------------------------------------------
// Gather-max kernels (bf16). R20/R21: one coalesced 64-index load per window
// + shfl broadcast (VMEM instrs per 64 edges: 64->33 / 32->17).
// R21 FIX: shfl (ds_bpermute) honors EXEC on the READ side — sources in an
// inactive sub-group return garbage. The sub-group loops diverge at window
// tails, so the index load is PERMUTED so each sub-group holds its own
// edges: gather50 lane (p,j) loads csr_src[ib + 2j + p] (edge k of parity p
// lives at lane 32p + (k>>1)); gather32 lane (e,c) loads csr_src[ib + 4c+e]
// (edge k =e mod 4 at lane 16e + (k>>2)). All shfl sources stay inside the
// executing sub-group -> safe under divergence. The 64 load addresses still
// cover [ib, ib+63] exactly -> same coalescing.

__global__ void gather50_kernel(const uint32* __restrict__ hb,
                                const int* __restrict__ offsets,
                                const int* __restrict__ csr_src,
                                uint32* __restrict__ aggB) {
    const int tid  = threadIdx.x;
    const int g    = tid >> 6;
    const int lane = tid & 63;
    const int p    = lane >> 5;        // half-wave: edge parity
    const int j    = lane & 31;        // uint chunk
    const int n    = blockIdx.x * NPB + g;
    if (n >= NN) return;

    const float NEG = -INFINITY;
    const int beg = offsets[n];
    const int end = offsets[n + 1];
    const char* hbase = (const char*)hb;
    const uint32 joff = (uint32)(j << 2);
    const int lb = p << 5;             // this half's lane base

    float lo_[8], hi_[8];
#pragma unroll
    for (int k = 0; k < 8; ++k) { lo_[k] = NEG; hi_[k] = NEG; }

    for (int ib = beg; ib < end; ib += 64) {
        const int rem = end - ib;
        const int mm  = rem < 64 ? rem : 64;
        const int myidx = 2 * j + p;               // this lane's edge in window
        int sidx = 0;
        if (myidx < mm) sidx = csr_src[ib + myidx];   // 1 coalesced VMEM / window
        int k = p;
        // 8 same-parity edges (16 edges per wave) in flight
        for (; k + 14 < mm; k += 16) {
            const int kh = lb + (k >> 1);
#pragma unroll
            for (int kk = 0; kk < 8; ++kk) {
                int s = __shfl(sidx, kh + kk);     // intra-half source
                uint32 u = *(const uint32*)(hbase + ((((uint32)s) << 7) | joff));
                lo_[kk] = fmaxf(lo_[kk], b2f_lo(u));
                hi_[kk] = fmaxf(hi_[kk], b2f_hi(u));
            }
        }
        // 4 edges
        for (; k + 6 < mm; k += 8) {
            const int kh = lb + (k >> 1);
#pragma unroll
            for (int kk = 0; kk < 4; ++kk) {
                int s = __shfl(sidx, kh + kk);
                uint32 u = *(const uint32*)(hbase + ((((uint32)s) << 7) | joff));
                lo_[kk] = fmaxf(lo_[kk], b2f_lo(u));
                hi_[kk] = fmaxf(hi_[kk], b2f_hi(u));
            }
        }
        // tail
        for (; k < mm; k += 2) {
            int s = __shfl(sidx, lb + (k >> 1));
            uint32 u = *(const uint32*)(hbase + ((((uint32)s) << 7) | joff));
            lo_[0] = fmaxf(lo_[0], b2f_lo(u));
            hi_[0] = fmaxf(hi_[0], b2f_hi(u));
        }
    }
#pragma unroll
    for (int off2 = 4; off2 > 0; off2 >>= 1)
#pragma unroll
        for (int k = 0; k < off2; ++k) {
            lo_[k] = fmaxf(lo_[k], lo_[k + off2]);
            hi_[k] = fmaxf(hi_[k], hi_[k + off2]);
        }
    float lo = lo_[0], hi = hi_[0];
    lo = fmaxf(lo, __shfl_xor(lo, 32));    // combine parity halves (converged)
    hi = fmaxf(hi, __shfl_xor(hi, 32));
    lo = (lo == NEG) ? 0.0f : lo;
    hi = (hi == NEG) ? 0.0f : hi;
    if (p == 0 && j < 25) {
        aggB[(size_t)n * 32 + j] =
            (__float_as_uint(lo) >> 16) | (__float_as_uint(hi) & 0xFFFF0000u);
    }
}

__global__ void gather32_kernel(const uint32* __restrict__ hb,
                                const int* __restrict__ offsets,
                                const int* __restrict__ csr_src,
                                uint32* __restrict__ aggB) {
    const int tid  = threadIdx.x;
    const int g    = tid >> 6;
    const int lane = tid & 63;
    const int e    = lane >> 4;        // quarter-wave: edge slot mod 4
    const int c    = lane & 15;        // uint chunk
    const int n    = blockIdx.x * NPB + g;
    if (n >= NN) return;

    const float NEG = -INFINITY;
    const int beg = offsets[n];
    const int end = offsets[n + 1];
    const char* hbase = (const char*)hb;
    const uint32 coff = (uint32)(c << 2);
    const int lb = e << 4;             // this quarter's lane base

    float l0 = NEG, h0 = NEG, l1 = NEG, h1 = NEG;
    float l2 = NEG, h2 = NEG, l3 = NEG, h3 = NEG;

    for (int ib = beg; ib < end; ib += 64) {
        const int rem = end - ib;
        const int mm  = rem < 64 ? rem : 64;
        const int myidx = 4 * c + e;               // this lane's edge in window
        int sidx = 0;
        if (myidx < mm) sidx = csr_src[ib + myidx];   // 1 coalesced VMEM / window
        int k = e;
        // 4 same-slot edges (16 edges per wave) in flight
        for (; k + 12 < mm; k += 16) {
            const int m = lb + (k >> 2);
            int s0 = __shfl(sidx, m);              // intra-quarter sources
            int s1 = __shfl(sidx, m + 1);
            int s2 = __shfl(sidx, m + 2);
            int s3 = __shfl(sidx, m + 3);
            uint32 u0 = *(const uint32*)(hbase + ((((uint32)s0) << 6) | coff));
            uint32 u1 = *(const uint32*)(hbase + ((((uint32)s1) << 6) | coff));
            uint32 u2 = *(const uint32*)(hbase + ((((uint32)s2) << 6) | coff));
            uint32 u3 = *(const uint32*)(hbase + ((((uint32)s3) << 6) | coff));
            l0 = fmaxf(l0, b2f_lo(u0)); h0 = fmaxf(h0, b2f_hi(u0));
            l1 = fmaxf(l1, b2f_lo(u1)); h1 = fmaxf(h1, b2f_hi(u1));
            l2 = fmaxf(l2, b2f_lo(u2)); h2 = fmaxf(h2, b2f_hi(u2));
            l3 = fmaxf(l3, b2f_lo(u3)); h3 = fmaxf(h3, b2f_hi(u3));
        }
        // tail
        for (; k < mm; k += 4) {
            int s = __shfl(sidx, lb + (k >> 2));
            uint32 u = *(const uint32*)(hbase + ((((uint32)s) << 6) | coff));
            l0 = fmaxf(l0, b2f_lo(u)); h0 = fmaxf(h0, b2f_hi(u));
        }
    }
    float lo = fmaxf(fmaxf(l0, l1), fmaxf(l2, l3));
    float hi = fmaxf(fmaxf(h0, h1), fmaxf(h2, h3));
    lo = fmaxf(lo, __shfl_xor(lo, 16));   // combine edge slots (converged)
    hi = fmaxf(hi, __shfl_xor(hi, 16));
    lo = fmaxf(lo, __shfl_xor(lo, 32));
    hi = fmaxf(hi, __shfl_xor(hi, 32));
    lo = (lo == NEG) ? 0.0f : lo;
    hi = (hi == NEG) ? 0.0f : hi;
    if (lane < 16) {
        aggB[(size_t)n * 16 + lane] =
            (__float_as_uint(lo) >> 16) | (__float_as_uint(hi) & 0xFFFF0000u);
    }
}

// ---------------------------------------------------------------------------
// Dense kernel (R11-proven): one lane per node; 32 fp32 accumulators; wave-
// uniform weight addresses scalarize to s_load (weights in SGPRs -> each FMA
// does 64 nodes of work, zero per-lane weight loads). MODE 0 = relu -> bf16;
// 2 = log_softmax -> fp32.
template <int DIN, int ASTR, int HSTR, int OSTR, int MODE>
__global__ void dense_kernel(const uint32* __restrict__ aggB,
                             const uint32* __restrict__ hB,
                             const float* __restrict__ Wl,
                             const float* __restrict__ bl,
                             const float* __restrict__ Wr,
                             void* __restrict__ out_v) {
    const int n = blockIdx.x * blockDim.x + threadIdx.x;
    if (n >= NN) return;

    float acc[CD];
#pragma unroll
    for (int j = 0; j < CD; ++j) acc[j] = bl[j];

    {
        const uint32* row = aggB + (size_t)n * ASTR;
        for (int c = 0; c < DIN / 4; ++c) {
            uint2 u = *(const uint2*)&row[c * 2];
            float d0 = b2f_lo(u.x), d1 = b2f_hi(u.x);
            float d2 = b2f_lo(u.y), d3 = b2f_hi(u.y);
            const float* w = Wl + c * 4 * CD;
#pragma unroll
            for (int j = 0; j < CD; ++j)
                acc[j] += d0 * w[j] + d1 * w[CD + j] + d2 * w[2 * CD + j] + d3 * w[3 * CD + j];
        }
        if (DIN % 4) {
            uint32 u = row[(DIN / 4) * 2];
            float d0 = b2f_lo(u), d1 = b2f_hi(u);
            const float* w = Wl + (DIN - 2) * CD;
#pragma unroll
            for (int j = 0; j < CD; ++j)
                acc[j] += d0 * w[j] + d1 * w[CD + j];
        }
    }
    {
        const uint32* row = hB + (size_t)n * HSTR;
        for (int c = 0; c < DIN / 4; ++c) {
            uint2 u = *(const uint2*)&row[c * 2];
            float d0 = b2f_lo(u.x), d1 = b2f_hi(u.x);
            float d2 = b2f_lo(u.y), d3 = b2f_hi(u.y);
            const float* w = Wr + c * 4 * CD;
#pragma unroll
            for (int j = 0; j < CD; ++j)
                acc[j] += d0 * w[j] + d1 * w[CD + j] + d2 * w[2 * CD + j] + d3 * w[3 * CD + j];
        }
        if (DIN % 4) {
            uint32 u = row[(DIN / 4) * 2];
            float d0 = b2f_lo(u), d1 = b2f_hi(u);
            const float* w = Wr + (DIN - 2) * CD;
#pragma unroll
            for (int j = 0; j < CD; ++j)
                acc[j] += d0 * w[j] + d1 * w[CD + j];
        }
    }

    if (MODE == 0) {
        uint32* orow = (uint32*)out_v + (size_t)n * OSTR;
#pragma unroll
        for (int c = 0; c < CD / 2; ++c) {
            float a0 = fmaxf(acc[2 * c],     0.0f);
            float a1 = fmaxf(acc[2 * c + 1], 0.0f);
            orow[c] = (uint32)f2b(a0) | ((uint32)f2b(a1) << 16);
        }
    } else {
        float m = acc[0];
#pragma unroll
        for (int j = 1; j < CD; ++j) m = fmaxf(m, acc[j]);
        float s = 0.0f;
#pragma unroll
        for (int j = 0; j < CD; ++j) s += expf(acc[j] - m);
        const float lse = m + logf(s);
        float* orow = (float*)out_v + (size_t)n * CD;
#pragma unroll
        for (int j = 0; j < CD; ++j) orow[j] = acc[j] - lse;
    }
}

// ---------------------------------------------------------------------------
extern "C" void kernel_launch(void* const* d_in, const int* in_sizes, int n_in,
                              void* d_out, int out_size, void* d_ws, size_t ws_size,
                              hipStream_t stream) {
    const float* x    = (const float*)d_in[0];
    const void*  edge = d_in[1];
    const float* Wl1 = (const float*)d_in[2];
    const float* bl1 = (const float*)d_in[3];
    const float* Wr1 = (const float*)d_in[4];
    const float* Wl2 = (const float*)d_in[5];
    const float* bl2 = (const float*)d_in[6];
    const float* Wr2 = (const float*)d_in[7];
    const float* Wl3 = (const float*)d_in[8];
    const float* bl3 = (const float*)d_in[9];
    const float* Wr3 = (const float*)d_in[10];

    const int E = in_sizes[1] / 2;

    // Workspace carve-up (256B aligned), ~26 MB. bucketed + hist live in
    // d_out (dead before agg1 is written there); h2b reuses xb (dead after
    // dense-L1); agg3 reuses h1b (dead after dense-L2).
    char* ws = (char*)d_ws;
    size_t off = 0;
    auto carve = [&](size_t bytes) {
        void* p = ws + off;
        off = (off + bytes + 255) & ~(size_t)255;
        return p;
    };
    int*    offsets   = (int*)   carve((size_t)(NN + 1) * 4);
    int*    binTotal  = (int*)   carve((size_t)B1N * 4);
    int*    csr_src   = (int*)   carve((size_t)E * 4);
    uint32* xb        = (uint32*)carve((size_t)NN * 32 * 4);  // 12.8 MB
    uint32* h1b       = (uint32*)carve((size_t)NN * 16 * 4);  // 6.4 MB
    (void)ws_size; (void)n_in; (void)out_size;

    uint32* bucketed = (uint32*)d_out;     // 6.4 MB, dead before agg1
    int*    hist     = (int*)((char*)d_out + (((size_t)E * 4 + 255) & ~(size_t)255));
    uint32* agg1 = (uint32*)d_out;         // L1 agg, stride 32 (12.8 MB = d_out)
    uint32* agg2 = (uint32*)d_out;         // L2 agg, stride 16
    uint32* h2b  = xb;                     // xb dead after dense-L1
    uint32* agg3 = h1b;                    // h1b dead after dense-L2

    cvt_x_kernel<<<(NN * 32 + 255) / 256, 256, 0, stream>>>(x, xb);

    // CSR build, LDS-atomic bucketing (no device-scope atomics, no memset).
    const int nblkA = (E + EPB_A - 1) / EPB_A;     // 782 for E=1.6M
    hist_kernel<<<nblkA, 256, 0, stream>>>(edge, E, hist);
    scanA_kernel<<<B1N, 256, 0, stream>>>(hist, nblkA, binTotal);
    scatter_kernel<<<nblkA, 256, 0, stream>>>(edge, E, hist, binTotal, bucketed);
    bucket_kernel<<<B1N, 256, 0, stream>>>(bucketed, binTotal, offsets, csr_src);

    const int gb = (NN + NPB - 1) / NPB;      // wave per node
    const int db = (NN + 255) / 256;          // lane per node

    // Layer 1: 50 -> 32, relu
    gather50_kernel<<<gb, 256, 0, stream>>>(xb, offsets, csr_src, agg1);
    dense_kernel<50, 32, 32, 16, 0><<<db, 256, 0, stream>>>(agg1, xb, Wl1, bl1, Wr1, h1b);
    // Layer 2: 32 -> 32, relu
    gather32_kernel<<<gb, 256, 0, stream>>>(h1b, offsets, csr_src, agg2);
    dense_kernel<32, 16, 16, 16, 0><<<db, 256, 0, stream>>>(agg2, h1b, Wl2, bl2, Wr2, h2b);
    // Layer 3: 32 -> 32, log_softmax -> fp32 d_out
    gather32_kernel<<<gb, 256, 0, stream>>>(h2b, offsets, csr_src, agg3);
    dense_kernel<32, 16, 16, 0, 2><<<db, 256, 0, stream>>>(agg3, h2b, Wl3, bl3, Wr3, d_out);
}

// Round 7
// 302.706 us; speedup vs baseline: 1.1533x; 1.0447x over previous
//
#include <hip/hip_runtime.h>
#include <math.h>

#define NN 100000      // nodes
#define CD 32          // classes / hidden
#define NPB 4          // nodes (waves) per block in gather kernels

#define B1N ((NN + 255) >> 8)   // 391 coarse buckets (256 nodes each)
#define EPB_A 2048              // edges per partition block (256 thr x 8)

typedef unsigned int   uint32;
typedef unsigned short ushort16;

// fp32 -> bf16 round-to-nearest-even
__device__ __forceinline__ ushort16 f2b(float f) {
    uint32 u = __float_as_uint(f);
    u = (u + 0x7FFFu + ((u >> 16) & 1u)) >> 16;
    return (ushort16)u;
}
// packed bf16 pair -> two fp32 (exact)
__device__ __forceinline__ float b2f_lo(uint32 u) { return __uint_as_float(u << 16); }
__device__ __forceinline__ float b2f_hi(uint32 u) { return __uint_as_float(u & 0xFFFF0000u); }

// ---------------------------------------------------------------------------
// R22: order-preserving bf16->u16 key space. key = b ^ (sign ? 0xFFFF :
// 0x8000) is strictly monotone in the float value, so max-of-keys ==
// key-of-max and the gather's per-uint max becomes ONE v_pk_max_u16
// (vs unpack-to-fp32 + 2 fmax = 5 VALU). Encode once in cvt (O(N));
// decode in dense loads (O(N), ~6 VALU/uint vs 3200 FMA/lane).
__device__ __forceinline__ uint32 pkmax(uint32 a, uint32 b) {
    uint32 d;
    asm("v_pk_max_u16 %0, %1, %2" : "=v"(d) : "v"(a), "v"(b));
    return d;
}
// fp32 -> bf16 key (scalar)
__device__ __forceinline__ uint32 key16(float f) {
    uint32 b = (uint32)f2b(f);
    return b ^ ((__float_as_uint(f) >> 31) ? 0xFFFFu : 0x8000u);
}
// packed key pair -> packed bf16 pair (general sign)
__device__ __forceinline__ uint32 dec_pk(uint32 k) {
    uint32 m = (~k >> 15) & 0x00010001u;            // 1 where original < 0
    uint32 X = 0x80008000u | ((m << 15) - m);       // per half: neg?0xFFFF:0x8000
    return k ^ X;
}

// Inline is64 detection (R17): every wave checks the first 512 values
// interpreted as i64; L2-hot after first block.
__device__ __forceinline__ int edge_is64(const void* edge) {
    const long long* p = (const long long*)edge;
    int lane = threadIdx.x & 63;
    int bad = 0;
    for (int i = lane; i < 512; i += 64) {
        long long v = p[i];
        if (v < 0 || v >= NN) bad = 1;
    }
    unsigned long long anybad = __ballot(bad);
    return (anybad == 0ULL) ? 1 : 0;
}

__device__ __forceinline__ int load_idx(const void* edge, int i, int is64) {
    if (is64) return (int)((const long long*)edge)[i];
    return ((const int*)edge)[i];
}

// ---------------------------------------------------------------------------
// Fused cvt + hist (independent work, one dispatch saved).
// cvt part: x (fp32, NN x 50) -> packed bf16-KEY rows, stride 32 uints
// (128 B cacheline-aligned; uints 25..31 zero pad = minimum key, never wins).
// hist part: per-block B1N-bin histogram of dst>>8 (LDS atomics).
__global__ __launch_bounds__(256) void cvt_hist_kernel(const float* __restrict__ x,
                                                       uint32* __restrict__ xb,
                                                       const void* edge, int E,
                                                       int* __restrict__ hist,
                                                       int nblkA) {
    __shared__ int lh[B1N];
    const int t = threadIdx.x;
    if ((int)blockIdx.x < nblkA) {
        const int is64 = edge_is64(edge);
        for (int b = t; b < B1N; b += 256) lh[b] = 0;
        __syncthreads();
        const int e0 = blockIdx.x * EPB_A + t;
#pragma unroll
        for (int k = 0; k < 8; ++k) {
            int e = e0 + k * 256;
            if (e < E) {
                int d = load_idx(edge, E + e, is64);
                atomicAdd(&lh[d >> 8], 1);
            }
        }
        __syncthreads();
        int* gh = hist + (size_t)blockIdx.x * B1N;
        for (int b = t; b < B1N; b += 256) gh[b] = lh[b];
    } else {
        const int tt = (blockIdx.x - nblkA) * 256 + t;
        if (tt >= NN * 32) return;
        const int n = tt >> 5;
        const int c = tt & 31;
        if (c >= 25) { xb[tt] = 0; return; }
        float2 v = *(const float2*)&x[n * 50 + 2 * c];
        xb[tt] = key16(v.x) | (key16(v.y) << 16);
    }
}

// One block per bin: exclusive scan of hist[b][bin] over blocks b (in place),
// bin total to binTotal[bin]. Supports nblk <= 1024 (4 per thread).
__global__ __launch_bounds__(256) void scanA_kernel(int* __restrict__ hist,
                                                    int nblk,
                                                    int* __restrict__ binTotal) {
    __shared__ int ts[256];
    const int bin = blockIdx.x;
    const int t = threadIdx.x;
    const int base = t * 4;
    int v0 = (base + 0 < nblk) ? hist[(size_t)(base + 0) * B1N + bin] : 0;
    int v1 = (base + 1 < nblk) ? hist[(size_t)(base + 1) * B1N + bin] : 0;
    int v2 = (base + 2 < nblk) ? hist[(size_t)(base + 2) * B1N + bin] : 0;
    int v3 = (base + 3 < nblk) ? hist[(size_t)(base + 3) * B1N + bin] : 0;
    const int s = v0 + v1 + v2 + v3;
    ts[t] = s;
    __syncthreads();
    for (int off = 1; off < 256; off <<= 1) {
        int u = (t >= off) ? ts[t - off] : 0;
        __syncthreads();
        ts[t] += u;
        __syncthreads();
    }
    int e = ts[t] - s;
    if (base + 0 < nblk) { hist[(size_t)(base + 0) * B1N + bin] = e; e += v0; }
    if (base + 1 < nblk) { hist[(size_t)(base + 1) * B1N + bin] = e; e += v1; }
    if (base + 2 < nblk) { hist[(size_t)(base + 2) * B1N + bin] = e; e += v2; }
    if (base + 3 < nblk) { hist[(size_t)(base + 3) * B1N + bin] = e; e += v3; }
    if (t == 255) binTotal[bin] = ts[255];
}

// In-block exclusive scan of binTotal[B1N] -> lbase[B1N+1] (LDS).
__device__ __forceinline__ void scan_bins_lds(const int* __restrict__ binTotal,
                                              int* ts, int* lbase) {
    const int t = threadIdx.x;
    const int base = t * 2;
    const int v0 = (base + 0 < B1N) ? binTotal[base + 0] : 0;
    const int v1 = (base + 1 < B1N) ? binTotal[base + 1] : 0;
    const int s = v0 + v1;
    ts[t] = s;
    __syncthreads();
    for (int off = 1; off < 256; off <<= 1) {
        int u = (t >= off) ? ts[t - off] : 0;
        __syncthreads();
        ts[t] += u;
        __syncthreads();
    }
    const int e = ts[t] - s;
    if (base + 0 < B1N) lbase[base + 0] = e;
    if (base + 1 < B1N) lbase[base + 1] = e + v0;
    if (t == 255) lbase[B1N] = ts[255];     // == E
    __syncthreads();
}

__global__ __launch_bounds__(256) void scatter_kernel(const void* edge, int E,
                                                      const int* __restrict__ hist,
                                                      const int* __restrict__ binTotal,
                                                      uint32* __restrict__ bucketed) {
    __shared__ int ts[256];
    __shared__ int lbase[B1N + 1];
    __shared__ int cur[B1N];
    const int is64 = edge_is64(edge);
    const int t = threadIdx.x;
    scan_bins_lds(binTotal, ts, lbase);
    const int* gh = hist + (size_t)blockIdx.x * B1N;
    for (int b = t; b < B1N; b += 256) cur[b] = lbase[b] + gh[b];
    __syncthreads();
    const int e0 = blockIdx.x * EPB_A + t;
#pragma unroll
    for (int k = 0; k < 8; ++k) {
        int e = e0 + k * 256;
        if (e < E) {
            int s = load_idx(edge, e, is64);
            int d = load_idx(edge, E + e, is64);
            int pos = atomicAdd(&cur[d >> 8], 1);   // LDS atomic
            bucketed[pos] = (uint32)s | ((uint32)(d & 255) << 17);
        }
    }
}

__global__ __launch_bounds__(256) void bucket_kernel(const uint32* __restrict__ bucketed,
                                                     const int* __restrict__ binTotal,
                                                     int* __restrict__ offsets,
                                                     int* __restrict__ csr_src) {
    __shared__ int ts[256];
    __shared__ int lbase[B1N + 1];
    __shared__ int h[256];
    __shared__ int sc[256];
    __shared__ int cur[256];
    const int bkt = blockIdx.x;
    const int t = threadIdx.x;
    scan_bins_lds(binTotal, ts, lbase);
    const int start = lbase[bkt];
    const int end   = lbase[bkt + 1];
    h[t] = 0;
    __syncthreads();
    for (int i = start + t; i < end; i += 256)
        atomicAdd(&h[bucketed[i] >> 17], 1);        // LDS atomic
    __syncthreads();
    const int v = h[t];
    sc[t] = v;
    __syncthreads();
    for (int off = 1; off < 256; off <<= 1) {
        int u = (t >= off) ? sc[t - off] : 0;
        __syncthreads();
        sc[t] += u;
        __syncthreads();
    }
    const int excl = sc[t] - v;
    const int node = bkt * 256 + t;
    if (node < NN) offsets[node] = start + excl;    // coalesced
    cur[t] = start + excl;
    __syncthreads();
    for (int i = start + t; i < end; i += 256) {
        uint32 p = bucketed[i];
        int pos = atomicAdd(&cur[p >> 17], 1);      // LDS atomic
        csr_src[pos] = (int)(p & 0x1FFFFu);         // L2-local scatter (16KB window)
    }
    if (bkt == B1N - 1 && t == 0) offsets[NN] = end;   // == E
}

// ---------------------------------------------------------------------------
// Gather-max kernels, key space (R22). R21's permuted coalesced index load +
// intra-sub-group shfl broadcast kept; per-uint max is now 1 v_pk_max_u16.
// Empty neighborhoods write key(+0.0)=0x80008000 (segment_max -> 0 rule).

__global__ void gather50_kernel(const uint32* __restrict__ hb,
                                const int* __restrict__ offsets,
                                const int* __restrict__ csr_src,
                                uint32* __restrict__ aggB) {
    const int tid  = threadIdx.x;
    const int g    = tid >> 6;
    const int lane = tid & 63;
    const int p    = lane >> 5;        // half-wave: edge parity
    const int j    = lane & 31;        // uint chunk
    const int n    = blockIdx.x * NPB + g;
    if (n >= NN) return;

    const int beg = offsets[n];
    const int end = offsets[n + 1];
    const char* hbase = (const char*)hb;
    const uint32 joff = (uint32)(j << 2);
    const int lb = p << 5;             // this half's lane base

    uint32 a_[8];
#pragma unroll
    for (int k = 0; k < 8; ++k) a_[k] = 0;          // minimum key

    for (int ib = beg; ib < end; ib += 64) {
        const int rem = end - ib;
        const int mm  = rem < 64 ? rem : 64;
        const int myidx = 2 * j + p;               // this lane's edge in window
        int sidx = 0;
        if (myidx < mm) sidx = csr_src[ib + myidx];   // 1 coalesced VMEM / window
        int k = p;
        for (; k + 14 < mm; k += 16) {
            const int kh = lb + (k >> 1);
#pragma unroll
            for (int kk = 0; kk < 8; ++kk) {
                int s = __shfl(sidx, kh + kk);     // intra-half source
                uint32 u = *(const uint32*)(hbase + ((((uint32)s) << 7) | joff));
                a_[kk] = pkmax(a_[kk], u);
            }
        }
        for (; k + 6 < mm; k += 8) {
            const int kh = lb + (k >> 1);
#pragma unroll
            for (int kk = 0; kk < 4; ++kk) {
                int s = __shfl(sidx, kh + kk);
                uint32 u = *(const uint32*)(hbase + ((((uint32)s) << 7) | joff));
                a_[kk] = pkmax(a_[kk], u);
            }
        }
        for (; k < mm; k += 2) {
            int s = __shfl(sidx, lb + (k >> 1));
            uint32 u = *(const uint32*)(hbase + ((((uint32)s) << 7) | joff));
            a_[0] = pkmax(a_[0], u);
        }
    }
#pragma unroll
    for (int off2 = 4; off2 > 0; off2 >>= 1)
#pragma unroll
        for (int k = 0; k < off2; ++k)
            a_[k] = pkmax(a_[k], a_[k + off2]);
    uint32 r = a_[0];
    r = pkmax(r, (uint32)__shfl_xor((int)r, 32));   // combine parity halves
    if (p == 0 && j < 25) {
        aggB[(size_t)n * 32 + j] = (beg == end) ? 0x80008000u : r;
    }
}

__global__ void gather32_kernel(const uint32* __restrict__ hb,
                                const int* __restrict__ offsets,
                                const int* __restrict__ csr_src,
                                uint32* __restrict__ aggB) {
    const int tid  = threadIdx.x;
    const int g    = tid >> 6;
    const int lane = tid & 63;
    const int e    = lane >> 4;        // quarter-wave: edge slot mod 4
    const int c    = lane & 15;        // uint chunk
    const int n    = blockIdx.x * NPB + g;
    if (n >= NN) return;

    const int beg = offsets[n];
    const int end = offsets[n + 1];
    const char* hbase = (const char*)hb;
    const uint32 coff = (uint32)(c << 2);
    const int lb = e << 4;             // this quarter's lane base

    uint32 a0 = 0, a1 = 0, a2 = 0, a3 = 0;

    for (int ib = beg; ib < end; ib += 64) {
        const int rem = end - ib;
        const int mm  = rem < 64 ? rem : 64;
        const int myidx = 4 * c + e;               // this lane's edge in window
        int sidx = 0;
        if (myidx < mm) sidx = csr_src[ib + myidx];   // 1 coalesced VMEM / window
        int k = e;
        for (; k + 12 < mm; k += 16) {
            const int m = lb + (k >> 2);
            int s0 = __shfl(sidx, m);              // intra-quarter sources
            int s1 = __shfl(sidx, m + 1);
            int s2 = __shfl(sidx, m + 2);
            int s3 = __shfl(sidx, m + 3);
            uint32 u0 = *(const uint32*)(hbase + ((((uint32)s0) << 6) | coff));
            uint32 u1 = *(const uint32*)(hbase + ((((uint32)s1) << 6) | coff));
            uint32 u2 = *(const uint32*)(hbase + ((((uint32)s2) << 6) | coff));
            uint32 u3 = *(const uint32*)(hbase + ((((uint32)s3) << 6) | coff));
            a0 = pkmax(a0, u0); a1 = pkmax(a1, u1);
            a2 = pkmax(a2, u2); a3 = pkmax(a3, u3);
        }
        for (; k < mm; k += 4) {
            int s = __shfl(sidx, lb + (k >> 2));
            uint32 u = *(const uint32*)(hbase + ((((uint32)s) << 6) | coff));
            a0 = pkmax(a0, u);
        }
    }
    uint32 r = pkmax(pkmax(a0, a1), pkmax(a2, a3));
    r = pkmax(r, (uint32)__shfl_xor((int)r, 16));   // combine edge slots
    r = pkmax(r, (uint32)__shfl_xor((int)r, 32));
    if (lane < 16) {
        aggB[(size_t)n * 16 + lane] = (beg == end) ? 0x80008000u : r;
    }
}

// ---------------------------------------------------------------------------
// Dense kernel (R11-proven): one lane per node; 32 fp32 accumulators; wave-
// uniform weight addresses scalarize to s_load. Inputs are key-encoded
// (dec_pk on load); MODE 0 stores relu output as keys (relu >= 0 -> encode
// is OR 0x80008000); MODE 2 = log_softmax -> fp32.
template <int DIN, int ASTR, int HSTR, int OSTR, int MODE>
__global__ void dense_kernel(const uint32* __restrict__ aggB,
                             const uint32* __restrict__ hB,
                             const float* __restrict__ Wl,
                             const float* __restrict__ bl,
                             const float* __restrict__ Wr,
                             void* __restrict__ out_v) {
    const int n = blockIdx.x * blockDim.x + threadIdx.x;
    if (n >= NN) return;

    float acc[CD];
#pragma unroll
    for (int j = 0; j < CD; ++j) acc[j] = bl[j];

    {
        const uint32* row = aggB + (size_t)n * ASTR;
        for (int c = 0; c < DIN / 4; ++c) {
            uint2 u = *(const uint2*)&row[c * 2];
            u.x = dec_pk(u.x); u.y = dec_pk(u.y);
            float d0 = b2f_lo(u.x), d1 = b2f_hi(u.x);
            float d2 = b2f_lo(u.y), d3 = b2f_hi(u.y);
            const float* w = Wl + c * 4 * CD;
#pragma unroll
            for (int j = 0; j < CD; ++j)
                acc[j] += d0 * w[j] + d1 * w[CD + j] + d2 * w[2 * CD + j] + d3 * w[3 * CD + j];
        }
        if (DIN % 4) {
            uint32 u = dec_pk(row[(DIN / 4) * 2]);
            float d0 = b2f_lo(u), d1 = b2f_hi(u);
            const float* w = Wl + (DIN - 2) * CD;
#pragma unroll
            for (int j = 0; j < CD; ++j)
                acc[j] += d0 * w[j] + d1 * w[CD + j];
        }
    }
    {
        const uint32* row = hB + (size_t)n * HSTR;
        for (int c = 0; c < DIN / 4; ++c) {
            uint2 u = *(const uint2*)&row[c * 2];
            u.x = dec_pk(u.x); u.y = dec_pk(u.y);
            float d0 = b2f_lo(u.x), d1 = b2f_hi(u.x);
            float d2 = b2f_lo(u.y), d3 = b2f_hi(u.y);
            const float* w = Wr + c * 4 * CD;
#pragma unroll
            for (int j = 0; j < CD; ++j)
                acc[j] += d0 * w[j] + d1 * w[CD + j] + d2 * w[2 * CD + j] + d3 * w[3 * CD + j];
        }
        if (DIN % 4) {
            uint32 u = dec_pk(row[(DIN / 4) * 2]);
            float d0 = b2f_lo(u), d1 = b2f_hi(u);
            const float* w = Wr + (DIN - 2) * CD;
#pragma unroll
            for (int j = 0; j < CD; ++j)
                acc[j] += d0 * w[j] + d1 * w[CD + j];
        }
    }

    if (MODE == 0) {
        uint32* orow = (uint32*)out_v + (size_t)n * OSTR;
#pragma unroll
        for (int c = 0; c < CD / 2; ++c) {
            float a0 = fmaxf(acc[2 * c],     0.0f);
            float a1 = fmaxf(acc[2 * c + 1], 0.0f);
            // relu output >= 0 -> key encode is just setting the top bit
            orow[c] = ((uint32)f2b(a0) | ((uint32)f2b(a1) << 16)) | 0x80008000u;
        }
    } else {
        float m = acc[0];
#pragma unroll
        for (int j = 1; j < CD; ++j) m = fmaxf(m, acc[j]);
        float s = 0.0f;
#pragma unroll
        for (int j = 0; j < CD; ++j) s += expf(acc[j] - m);
        const float lse = m + logf(s);
        float* orow = (float*)out_v + (size_t)n * CD;
#pragma unroll
        for (int j = 0; j < CD; ++j) orow[j] = acc[j] - lse;
    }
}

// ---------------------------------------------------------------------------
extern "C" void kernel_launch(void* const* d_in, const int* in_sizes, int n_in,
                              void* d_out, int out_size, void* d_ws, size_t ws_size,
                              hipStream_t stream) {
    const float* x    = (const float*)d_in[0];
    const void*  edge = d_in[1];
    const float* Wl1 = (const float*)d_in[2];
    const float* bl1 = (const float*)d_in[3];
    const float* Wr1 = (const float*)d_in[4];
    const float* Wl2 = (const float*)d_in[5];
    const float* bl2 = (const float*)d_in[6];
    const float* Wr2 = (const float*)d_in[7];
    const float* Wl3 = (const float*)d_in[8];
    const float* bl3 = (const float*)d_in[9];
    const float* Wr3 = (const float*)d_in[10];

    const int E = in_sizes[1] / 2;

    // Workspace carve-up (256B aligned), ~26 MB. bucketed + hist live in
    // d_out (dead before agg1 is written there); h2b reuses xb (dead after
    // dense-L1); agg3 reuses h1b (dead after dense-L2).
    char* ws = (char*)d_ws;
    size_t off = 0;
    auto carve = [&](size_t bytes) {
        void* p = ws + off;
        off = (off + bytes + 255) & ~(size_t)255;
        return p;
    };
    int*    offsets   = (int*)   carve((size_t)(NN + 1) * 4);
    int*    binTotal  = (int*)   carve((size_t)B1N * 4);
    int*    csr_src   = (int*)   carve((size_t)E * 4);
    uint32* xb        = (uint32*)carve((size_t)NN * 32 * 4);  // 12.8 MB
    uint32* h1b       = (uint32*)carve((size_t)NN * 16 * 4);  // 6.4 MB
    (void)ws_size; (void)n_in; (void)out_size;

    uint32* bucketed = (uint32*)d_out;     // 6.4 MB, dead before agg1
    int*    hist     = (int*)((char*)d_out + (((size_t)E * 4 + 255) & ~(size_t)255));
    uint32* agg1 = (uint32*)d_out;         // L1 agg, stride 32 (12.8 MB = d_out)
    uint32* agg2 = (uint32*)d_out;         // L2 agg, stride 16
    uint32* h2b  = xb;                     // xb dead after dense-L1
    uint32* agg3 = h1b;                    // h1b dead after dense-L2

    // CSR build, LDS-atomic bucketing (no device-scope atomics, no memset);
    // cvt fused into the hist dispatch (independent work).
    const int nblkA = (E + EPB_A - 1) / EPB_A;     // 782 for E=1.6M
    const int cvtb  = (NN * 32 + 255) / 256;       // 12500
    cvt_hist_kernel<<<nblkA + cvtb, 256, 0, stream>>>(x, xb, edge, E, hist, nblkA);
    scanA_kernel<<<B1N, 256, 0, stream>>>(hist, nblkA, binTotal);
    scatter_kernel<<<nblkA, 256, 0, stream>>>(edge, E, hist, binTotal, bucketed);
    bucket_kernel<<<B1N, 256, 0, stream>>>(bucketed, binTotal, offsets, csr_src);

    const int gb = (NN + NPB - 1) / NPB;      // wave per node
    const int db = (NN + 255) / 256;          // lane per node

    // Layer 1: 50 -> 32, relu
    gather50_kernel<<<gb, 256, 0, stream>>>(xb, offsets, csr_src, agg1);
    dense_kernel<50, 32, 32, 16, 0><<<db, 256, 0, stream>>>(agg1, xb, Wl1, bl1, Wr1, h1b);
    // Layer 2: 32 -> 32, relu
    gather32_kernel<<<gb, 256, 0, stream>>>(h1b, offsets, csr_src, agg2);
    dense_kernel<32, 16, 16, 16, 0><<<db, 256, 0, stream>>>(agg2, h1b, Wl2, bl2, Wr2, h2b);
    // Layer 3: 32 -> 32, log_softmax -> fp32 d_out
    gather32_kernel<<<gb, 256, 0, stream>>>(h2b, offsets, csr_src, agg3);
    dense_kernel<32, 16, 16, 0, 2><<<db, 256, 0, stream>>>(agg3, h2b, Wl3, bl3, Wr3, d_out);
}

// Round 8
// 289.237 us; speedup vs baseline: 1.2070x; 1.0466x over previous
//
#include <hip/hip_runtime.h>
#include <math.h>

#define NN 100000      // nodes
#define CD 32          // classes / hidden
#define NPB 4          // waves per block in gather kernels (2 nodes per wave)

#define B1N ((NN + 255) >> 8)   // 391 coarse buckets (256 nodes each)
#define EPB_A 2048              // edges per partition block (256 thr x 8)

typedef unsigned int   uint32;
typedef unsigned short ushort16;

// fp32 -> bf16 round-to-nearest-even
__device__ __forceinline__ ushort16 f2b(float f) {
    uint32 u = __float_as_uint(f);
    u = (u + 0x7FFFu + ((u >> 16) & 1u)) >> 16;
    return (ushort16)u;
}
// packed bf16 pair -> two fp32 (exact)
__device__ __forceinline__ float b2f_lo(uint32 u) { return __uint_as_float(u << 16); }
__device__ __forceinline__ float b2f_hi(uint32 u) { return __uint_as_float(u & 0xFFFF0000u); }

// ---------------------------------------------------------------------------
// R22: order-preserving bf16->u16 key space (max-of-keys == key-of-max);
// per-uint gather max = ONE v_pk_max_u16.
__device__ __forceinline__ uint32 pkmax(uint32 a, uint32 b) {
    uint32 d;
    asm("v_pk_max_u16 %0, %1, %2" : "=v"(d) : "v"(a), "v"(b));
    return d;
}
// fp32 -> bf16 key (scalar)
__device__ __forceinline__ uint32 key16(float f) {
    uint32 b = (uint32)f2b(f);
    return b ^ ((__float_as_uint(f) >> 31) ? 0xFFFFu : 0x8000u);
}
// packed key pair -> packed bf16 pair (general sign)
__device__ __forceinline__ uint32 dec_pk(uint32 k) {
    uint32 m = (~k >> 15) & 0x00010001u;            // 1 where original < 0
    uint32 X = 0x80008000u | ((m << 15) - m);       // per half: neg?0xFFFF:0x8000
    return k ^ X;
}

// Inline is64 detection (R17).
__device__ __forceinline__ int edge_is64(const void* edge) {
    const long long* p = (const long long*)edge;
    int lane = threadIdx.x & 63;
    int bad = 0;
    for (int i = lane; i < 512; i += 64) {
        long long v = p[i];
        if (v < 0 || v >= NN) bad = 1;
    }
    unsigned long long anybad = __ballot(bad);
    return (anybad == 0ULL) ? 1 : 0;
}

__device__ __forceinline__ int load_idx(const void* edge, int i, int is64) {
    if (is64) return (int)((const long long*)edge)[i];
    return ((const int*)edge)[i];
}

// ---------------------------------------------------------------------------
// Fused cvt + hist (R22).
__global__ __launch_bounds__(256) void cvt_hist_kernel(const float* __restrict__ x,
                                                       uint32* __restrict__ xb,
                                                       const void* edge, int E,
                                                       int* __restrict__ hist,
                                                       int nblkA) {
    __shared__ int lh[B1N];
    const int t = threadIdx.x;
    if ((int)blockIdx.x < nblkA) {
        const int is64 = edge_is64(edge);
        for (int b = t; b < B1N; b += 256) lh[b] = 0;
        __syncthreads();
        const int e0 = blockIdx.x * EPB_A + t;
#pragma unroll
        for (int k = 0; k < 8; ++k) {
            int e = e0 + k * 256;
            if (e < E) {
                int d = load_idx(edge, E + e, is64);
                atomicAdd(&lh[d >> 8], 1);
            }
        }
        __syncthreads();
        int* gh = hist + (size_t)blockIdx.x * B1N;
        for (int b = t; b < B1N; b += 256) gh[b] = lh[b];
    } else {
        const int tt = (blockIdx.x - nblkA) * 256 + t;
        if (tt >= NN * 32) return;
        const int n = tt >> 5;
        const int c = tt & 31;
        if (c >= 25) { xb[tt] = 0; return; }
        float2 v = *(const float2*)&x[n * 50 + 2 * c];
        xb[tt] = key16(v.x) | (key16(v.y) << 16);
    }
}

// One block per bin: exclusive scan of hist[b][bin] over blocks b (in place),
// bin total to binTotal[bin]. Supports nblk <= 1024 (4 per thread).
__global__ __launch_bounds__(256) void scanA_kernel(int* __restrict__ hist,
                                                    int nblk,
                                                    int* __restrict__ binTotal) {
    __shared__ int ts[256];
    const int bin = blockIdx.x;
    const int t = threadIdx.x;
    const int base = t * 4;
    int v0 = (base + 0 < nblk) ? hist[(size_t)(base + 0) * B1N + bin] : 0;
    int v1 = (base + 1 < nblk) ? hist[(size_t)(base + 1) * B1N + bin] : 0;
    int v2 = (base + 2 < nblk) ? hist[(size_t)(base + 2) * B1N + bin] : 0;
    int v3 = (base + 3 < nblk) ? hist[(size_t)(base + 3) * B1N + bin] : 0;
    const int s = v0 + v1 + v2 + v3;
    ts[t] = s;
    __syncthreads();
    for (int off = 1; off < 256; off <<= 1) {
        int u = (t >= off) ? ts[t - off] : 0;
        __syncthreads();
        ts[t] += u;
        __syncthreads();
    }
    int e = ts[t] - s;
    if (base + 0 < nblk) { hist[(size_t)(base + 0) * B1N + bin] = e; e += v0; }
    if (base + 1 < nblk) { hist[(size_t)(base + 1) * B1N + bin] = e; e += v1; }
    if (base + 2 < nblk) { hist[(size_t)(base + 2) * B1N + bin] = e; e += v2; }
    if (base + 3 < nblk) { hist[(size_t)(base + 3) * B1N + bin] = e; e += v3; }
    if (t == 255) binTotal[bin] = ts[255];
}

// In-block exclusive scan of binTotal[B1N] -> lbase[B1N+1] (LDS).
__device__ __forceinline__ void scan_bins_lds(const int* __restrict__ binTotal,
                                              int* ts, int* lbase) {
    const int t = threadIdx.x;
    const int base = t * 2;
    const int v0 = (base + 0 < B1N) ? binTotal[base + 0] : 0;
    const int v1 = (base + 1 < B1N) ? binTotal[base + 1] : 0;
    const int s = v0 + v1;
    ts[t] = s;
    __syncthreads();
    for (int off = 1; off < 256; off <<= 1) {
        int u = (t >= off) ? ts[t - off] : 0;
        __syncthreads();
        ts[t] += u;
        __syncthreads();
    }
    const int e = ts[t] - s;
    if (base + 0 < B1N) lbase[base + 0] = e;
    if (base + 1 < B1N) lbase[base + 1] = e + v0;
    if (t == 255) lbase[B1N] = ts[255];     // == E
    __syncthreads();
}

__global__ __launch_bounds__(256) void scatter_kernel(const void* edge, int E,
                                                      const int* __restrict__ hist,
                                                      const int* __restrict__ binTotal,
                                                      uint32* __restrict__ bucketed) {
    __shared__ int ts[256];
    __shared__ int lbase[B1N + 1];
    __shared__ int cur[B1N];
    const int is64 = edge_is64(edge);
    const int t = threadIdx.x;
    scan_bins_lds(binTotal, ts, lbase);
    const int* gh = hist + (size_t)blockIdx.x * B1N;
    for (int b = t; b < B1N; b += 256) cur[b] = lbase[b] + gh[b];
    __syncthreads();
    const int e0 = blockIdx.x * EPB_A + t;
#pragma unroll
    for (int k = 0; k < 8; ++k) {
        int e = e0 + k * 256;
        if (e < E) {
            int s = load_idx(edge, e, is64);
            int d = load_idx(edge, E + e, is64);
            int pos = atomicAdd(&cur[d >> 8], 1);   // LDS atomic
            bucketed[pos] = (uint32)s | ((uint32)(d & 255) << 17);
        }
    }
}

__global__ __launch_bounds__(256) void bucket_kernel(const uint32* __restrict__ bucketed,
                                                     const int* __restrict__ binTotal,
                                                     int* __restrict__ offsets,
                                                     int* __restrict__ csr_src) {
    __shared__ int ts[256];
    __shared__ int lbase[B1N + 1];
    __shared__ int h[256];
    __shared__ int sc[256];
    __shared__ int cur[256];
    const int bkt = blockIdx.x;
    const int t = threadIdx.x;
    scan_bins_lds(binTotal, ts, lbase);
    const int start = lbase[bkt];
    const int end   = lbase[bkt + 1];
    h[t] = 0;
    __syncthreads();
    for (int i = start + t; i < end; i += 256)
        atomicAdd(&h[bucketed[i] >> 17], 1);        // LDS atomic
    __syncthreads();
    const int v = h[t];
    sc[t] = v;
    __syncthreads();
    for (int off = 1; off < 256; off <<= 1) {
        int u = (t >= off) ? sc[t - off] : 0;
        __syncthreads();
        sc[t] += u;
        __syncthreads();
    }
    const int excl = sc[t] - v;
    const int node = bkt * 256 + t;
    if (node < NN) offsets[node] = start + excl;    // coalesced
    cur[t] = start + excl;
    __syncthreads();
    for (int i = start + t; i < end; i += 256) {
        uint32 p = bucketed[i];
        int pos = atomicAdd(&cur[p >> 17], 1);      // LDS atomic
        csr_src[pos] = (int)(p & 0x1FFFFu);         // L2-local scatter (16KB window)
    }
    if (bkt == B1N - 1 && t == 0) offsets[NN] = end;   // == E
}

// ---------------------------------------------------------------------------
// Gather-max kernels, key space. R23: TWO nodes per wave, software-pipelined.
// The gather is latency-bound: per node, the index-window load must complete
// before any row load can issue (shfl dependency) -> 2 serialized latency
// rounds/node. Issuing node0's AND node1's index loads back-to-back lets
// node1's indices arrive under node0's row round (~1.2 rounds/node).
// Multi-window nodes (degree>64, ~never at Poisson-16) take per-node loops.

__device__ __forceinline__ void g50_window(uint32* a_, int sidx, int mm,
                                           const char* hbase, uint32 joff,
                                           int p, int lb) {
    int k = p;
    for (; k + 14 < mm; k += 16) {
        const int kh = lb + (k >> 1);
#pragma unroll
        for (int kk = 0; kk < 8; ++kk) {
            int s = __shfl(sidx, kh + kk);     // intra-half source (R21 layout)
            uint32 u = *(const uint32*)(hbase + ((((uint32)s) << 7) | joff));
            a_[kk] = pkmax(a_[kk], u);
        }
    }
    for (; k + 6 < mm; k += 8) {
        const int kh = lb + (k >> 1);
#pragma unroll
        for (int kk = 0; kk < 4; ++kk) {
            int s = __shfl(sidx, kh + kk);
            uint32 u = *(const uint32*)(hbase + ((((uint32)s) << 7) | joff));
            a_[kk] = pkmax(a_[kk], u);
        }
    }
    for (; k < mm; k += 2) {
        int s = __shfl(sidx, lb + (k >> 1));
        uint32 u = *(const uint32*)(hbase + ((((uint32)s) << 7) | joff));
        a_[0] = pkmax(a_[0], u);
    }
}

__global__ void gather50_kernel(const uint32* __restrict__ hb,
                                const int* __restrict__ offsets,
                                const int* __restrict__ csr_src,
                                uint32* __restrict__ aggB) {
    const int tid  = threadIdx.x;
    const int g    = tid >> 6;
    const int lane = tid & 63;
    const int p    = lane >> 5;        // half-wave: edge parity
    const int j    = lane & 31;        // uint chunk
    const int n0   = (blockIdx.x * NPB + g) * 2;
    if (n0 >= NN) return;
    const int n1   = n0 + 1;
    const bool has1 = (n1 < NN);

    const int beg0 = offsets[n0];
    const int end0 = offsets[n0 + 1];
    const int beg1 = has1 ? offsets[n1] : 0;
    const int end1 = has1 ? offsets[n1 + 1] : 0;
    const char* hbase = (const char*)hb;
    const uint32 joff = (uint32)(j << 2);
    const int lb = p << 5;             // this half's lane base
    const int myidx = 2 * j + p;       // R21 permuted window layout

    uint32 a_[8], b_[8];
#pragma unroll
    for (int k = 0; k < 8; ++k) { a_[k] = 0; b_[k] = 0; }

    // First windows of both nodes: issue BOTH index loads before any rows.
    const int d0 = end0 - beg0, d1 = end1 - beg1;
    const int mm0 = d0 < 64 ? d0 : 64;
    const int mm1 = d1 < 64 ? d1 : 64;
    int sidx0 = 0, sidx1 = 0;
    if (myidx < mm0) sidx0 = csr_src[beg0 + myidx];
    if (myidx < mm1) sidx1 = csr_src[beg1 + myidx];
    g50_window(a_, sidx0, mm0, hbase, joff, p, lb);
    g50_window(b_, sidx1, mm1, hbase, joff, p, lb);
    // Rare extra windows (degree > 64)
    for (int ib = beg0 + 64; ib < end0; ib += 64) {
        const int rem = end0 - ib;
        const int mm = rem < 64 ? rem : 64;
        int s = (myidx < mm) ? csr_src[ib + myidx] : 0;
        g50_window(a_, s, mm, hbase, joff, p, lb);
    }
    for (int ib = beg1 + 64; ib < end1; ib += 64) {
        const int rem = end1 - ib;
        const int mm = rem < 64 ? rem : 64;
        int s = (myidx < mm) ? csr_src[ib + myidx] : 0;
        g50_window(b_, s, mm, hbase, joff, p, lb);
    }

#pragma unroll
    for (int off2 = 4; off2 > 0; off2 >>= 1)
#pragma unroll
        for (int k = 0; k < off2; ++k) {
            a_[k] = pkmax(a_[k], a_[k + off2]);
            b_[k] = pkmax(b_[k], b_[k + off2]);
        }
    uint32 r0 = a_[0], r1 = b_[0];
    r0 = pkmax(r0, (uint32)__shfl_xor((int)r0, 32));   // combine parity halves
    r1 = pkmax(r1, (uint32)__shfl_xor((int)r1, 32));
    if (p == 0 && j < 25) {
        aggB[(size_t)n0 * 32 + j] = (beg0 == end0) ? 0x80008000u : r0;
        if (has1)
            aggB[(size_t)n1 * 32 + j] = (beg1 == end1) ? 0x80008000u : r1;
    }
}

__device__ __forceinline__ void g32_window(uint32* a_, int sidx, int mm,
                                           const char* hbase, uint32 coff,
                                           int e, int lb) {
    int k = e;
    for (; k + 12 < mm; k += 16) {
        const int m = lb + (k >> 2);
        int s0 = __shfl(sidx, m);              // intra-quarter sources
        int s1 = __shfl(sidx, m + 1);
        int s2 = __shfl(sidx, m + 2);
        int s3 = __shfl(sidx, m + 3);
        uint32 u0 = *(const uint32*)(hbase + ((((uint32)s0) << 6) | coff));
        uint32 u1 = *(const uint32*)(hbase + ((((uint32)s1) << 6) | coff));
        uint32 u2 = *(const uint32*)(hbase + ((((uint32)s2) << 6) | coff));
        uint32 u3 = *(const uint32*)(hbase + ((((uint32)s3) << 6) | coff));
        a_[0] = pkmax(a_[0], u0); a_[1] = pkmax(a_[1], u1);
        a_[2] = pkmax(a_[2], u2); a_[3] = pkmax(a_[3], u3);
    }
    for (; k < mm; k += 4) {
        int s = __shfl(sidx, lb + (k >> 2));
        uint32 u = *(const uint32*)(hbase + ((((uint32)s) << 6) | coff));
        a_[0] = pkmax(a_[0], u);
    }
}

__global__ void gather32_kernel(const uint32* __restrict__ hb,
                                const int* __restrict__ offsets,
                                const int* __restrict__ csr_src,
                                uint32* __restrict__ aggB) {
    const int tid  = threadIdx.x;
    const int g    = tid >> 6;
    const int lane = tid & 63;
    const int e    = lane >> 4;        // quarter-wave: edge slot mod 4
    const int c    = lane & 15;        // uint chunk
    const int n0   = (blockIdx.x * NPB + g) * 2;
    if (n0 >= NN) return;
    const int n1   = n0 + 1;
    const bool has1 = (n1 < NN);

    const int beg0 = offsets[n0];
    const int end0 = offsets[n0 + 1];
    const int beg1 = has1 ? offsets[n1] : 0;
    const int end1 = has1 ? offsets[n1 + 1] : 0;
    const char* hbase = (const char*)hb;
    const uint32 coff = (uint32)(c << 2);
    const int lb = e << 4;             // this quarter's lane base
    const int myidx = 4 * c + e;       // R21 permuted window layout

    uint32 a_[4] = {0, 0, 0, 0};
    uint32 b_[4] = {0, 0, 0, 0};

    const int d0 = end0 - beg0, d1 = end1 - beg1;
    const int mm0 = d0 < 64 ? d0 : 64;
    const int mm1 = d1 < 64 ? d1 : 64;
    int sidx0 = 0, sidx1 = 0;
    if (myidx < mm0) sidx0 = csr_src[beg0 + myidx];
    if (myidx < mm1) sidx1 = csr_src[beg1 + myidx];
    g32_window(a_, sidx0, mm0, hbase, coff, e, lb);
    g32_window(b_, sidx1, mm1, hbase, coff, e, lb);
    for (int ib = beg0 + 64; ib < end0; ib += 64) {
        const int rem = end0 - ib;
        const int mm = rem < 64 ? rem : 64;
        int s = (myidx < mm) ? csr_src[ib + myidx] : 0;
        g32_window(a_, s, mm, hbase, coff, e, lb);
    }
    for (int ib = beg1 + 64; ib < end1; ib += 64) {
        const int rem = end1 - ib;
        const int mm = rem < 64 ? rem : 64;
        int s = (myidx < mm) ? csr_src[ib + myidx] : 0;
        g32_window(b_, s, mm, hbase, coff, e, lb);
    }

    uint32 r0 = pkmax(pkmax(a_[0], a_[1]), pkmax(a_[2], a_[3]));
    uint32 r1 = pkmax(pkmax(b_[0], b_[1]), pkmax(b_[2], b_[3]));
    r0 = pkmax(r0, (uint32)__shfl_xor((int)r0, 16));   // combine edge slots
    r0 = pkmax(r0, (uint32)__shfl_xor((int)r0, 32));
    r1 = pkmax(r1, (uint32)__shfl_xor((int)r1, 16));
    r1 = pkmax(r1, (uint32)__shfl_xor((int)r1, 32));
    if (lane < 16) {
        aggB[(size_t)n0 * 16 + lane] = (beg0 == end0) ? 0x80008000u : r0;
        if (has1)
            aggB[(size_t)n1 * 16 + lane] = (beg1 == end1) ? 0x80008000u : r1;
    }
}

// ---------------------------------------------------------------------------
// Dense kernel (R11-proven): one lane per node; 32 fp32 accumulators; wave-
// uniform weight addresses scalarize to s_load. Inputs key-encoded (dec_pk
// on load); MODE 0 stores relu output as keys (relu >= 0 -> OR 0x80008000);
// MODE 2 = log_softmax -> fp32.
template <int DIN, int ASTR, int HSTR, int OSTR, int MODE>
__global__ void dense_kernel(const uint32* __restrict__ aggB,
                             const uint32* __restrict__ hB,
                             const float* __restrict__ Wl,
                             const float* __restrict__ bl,
                             const float* __restrict__ Wr,
                             void* __restrict__ out_v) {
    const int n = blockIdx.x * blockDim.x + threadIdx.x;
    if (n >= NN) return;

    float acc[CD];
#pragma unroll
    for (int j = 0; j < CD; ++j) acc[j] = bl[j];

    {
        const uint32* row = aggB + (size_t)n * ASTR;
        for (int c = 0; c < DIN / 4; ++c) {
            uint2 u = *(const uint2*)&row[c * 2];
            u.x = dec_pk(u.x); u.y = dec_pk(u.y);
            float d0 = b2f_lo(u.x), d1 = b2f_hi(u.x);
            float d2 = b2f_lo(u.y), d3 = b2f_hi(u.y);
            const float* w = Wl + c * 4 * CD;
#pragma unroll
            for (int j = 0; j < CD; ++j)
                acc[j] += d0 * w[j] + d1 * w[CD + j] + d2 * w[2 * CD + j] + d3 * w[3 * CD + j];
        }
        if (DIN % 4) {
            uint32 u = dec_pk(row[(DIN / 4) * 2]);
            float d0 = b2f_lo(u), d1 = b2f_hi(u);
            const float* w = Wl + (DIN - 2) * CD;
#pragma unroll
            for (int j = 0; j < CD; ++j)
                acc[j] += d0 * w[j] + d1 * w[CD + j];
        }
    }
    {
        const uint32* row = hB + (size_t)n * HSTR;
        for (int c = 0; c < DIN / 4; ++c) {
            uint2 u = *(const uint2*)&row[c * 2];
            u.x = dec_pk(u.x); u.y = dec_pk(u.y);
            float d0 = b2f_lo(u.x), d1 = b2f_hi(u.x);
            float d2 = b2f_lo(u.y), d3 = b2f_hi(u.y);
            const float* w = Wr + c * 4 * CD;
#pragma unroll
            for (int j = 0; j < CD; ++j)
                acc[j] += d0 * w[j] + d1 * w[CD + j] + d2 * w[2 * CD + j] + d3 * w[3 * CD + j];
        }
        if (DIN % 4) {
            uint32 u = dec_pk(row[(DIN / 4) * 2]);
            float d0 = b2f_lo(u), d1 = b2f_hi(u);
            const float* w = Wr + (DIN - 2) * CD;
#pragma unroll
            for (int j = 0; j < CD; ++j)
                acc[j] += d0 * w[j] + d1 * w[CD + j];
        }
    }

    if (MODE == 0) {
        uint32* orow = (uint32*)out_v + (size_t)n * OSTR;
#pragma unroll
        for (int c = 0; c < CD / 2; ++c) {
            float a0 = fmaxf(acc[2 * c],     0.0f);
            float a1 = fmaxf(acc[2 * c + 1], 0.0f);
            // relu output >= 0 -> key encode is just setting the top bit
            orow[c] = ((uint32)f2b(a0) | ((uint32)f2b(a1) << 16)) | 0x80008000u;
        }
    } else {
        float m = acc[0];
#pragma unroll
        for (int j = 1; j < CD; ++j) m = fmaxf(m, acc[j]);
        float s = 0.0f;
#pragma unroll
        for (int j = 0; j < CD; ++j) s += expf(acc[j] - m);
        const float lse = m + logf(s);
        float* orow = (float*)out_v + (size_t)n * CD;
#pragma unroll
        for (int j = 0; j < CD; ++j) orow[j] = acc[j] - lse;
    }
}

// ---------------------------------------------------------------------------
extern "C" void kernel_launch(void* const* d_in, const int* in_sizes, int n_in,
                              void* d_out, int out_size, void* d_ws, size_t ws_size,
                              hipStream_t stream) {
    const float* x    = (const float*)d_in[0];
    const void*  edge = d_in[1];
    const float* Wl1 = (const float*)d_in[2];
    const float* bl1 = (const float*)d_in[3];
    const float* Wr1 = (const float*)d_in[4];
    const float* Wl2 = (const float*)d_in[5];
    const float* bl2 = (const float*)d_in[6];
    const float* Wr2 = (const float*)d_in[7];
    const float* Wl3 = (const float*)d_in[8];
    const float* bl3 = (const float*)d_in[9];
    const float* Wr3 = (const float*)d_in[10];

    const int E = in_sizes[1] / 2;

    // Workspace carve-up (256B aligned), ~26 MB. bucketed + hist live in
    // d_out (dead before agg1 is written there); h2b reuses xb (dead after
    // dense-L1); agg3 reuses h1b (dead after dense-L2).
    char* ws = (char*)d_ws;
    size_t off = 0;
    auto carve = [&](size_t bytes) {
        void* p = ws + off;
        off = (off + bytes + 255) & ~(size_t)255;
        return p;
    };
    int*    offsets   = (int*)   carve((size_t)(NN + 1) * 4);
    int*    binTotal  = (int*)   carve((size_t)B1N * 4);
    int*    csr_src   = (int*)   carve((size_t)E * 4);
    uint32* xb        = (uint32*)carve((size_t)NN * 32 * 4);  // 12.8 MB
    uint32* h1b       = (uint32*)carve((size_t)NN * 16 * 4);  // 6.4 MB
    (void)ws_size; (void)n_in; (void)out_size;

    uint32* bucketed = (uint32*)d_out;     // 6.4 MB, dead before agg1
    int*    hist     = (int*)((char*)d_out + (((size_t)E * 4 + 255) & ~(size_t)255));
    uint32* agg1 = (uint32*)d_out;         // L1 agg, stride 32 (12.8 MB = d_out)
    uint32* agg2 = (uint32*)d_out;         // L2 agg, stride 16
    uint32* h2b  = xb;                     // xb dead after dense-L1
    uint32* agg3 = h1b;                    // h1b dead after dense-L2

    // CSR build, LDS-atomic bucketing; cvt fused into the hist dispatch.
    const int nblkA = (E + EPB_A - 1) / EPB_A;     // 782 for E=1.6M
    const int cvtb  = (NN * 32 + 255) / 256;       // 12500
    cvt_hist_kernel<<<nblkA + cvtb, 256, 0, stream>>>(x, xb, edge, E, hist, nblkA);
    scanA_kernel<<<B1N, 256, 0, stream>>>(hist, nblkA, binTotal);
    scatter_kernel<<<nblkA, 256, 0, stream>>>(edge, E, hist, binTotal, bucketed);
    bucket_kernel<<<B1N, 256, 0, stream>>>(bucketed, binTotal, offsets, csr_src);

    const int gb = (NN + NPB * 2 - 1) / (NPB * 2);   // 2 nodes per wave
    const int db = (NN + 255) / 256;                 // lane per node

    // Layer 1: 50 -> 32, relu
    gather50_kernel<<<gb, 256, 0, stream>>>(xb, offsets, csr_src, agg1);
    dense_kernel<50, 32, 32, 16, 0><<<db, 256, 0, stream>>>(agg1, xb, Wl1, bl1, Wr1, h1b);
    // Layer 2: 32 -> 32, relu
    gather32_kernel<<<gb, 256, 0, stream>>>(h1b, offsets, csr_src, agg2);
    dense_kernel<32, 16, 16, 16, 0><<<db, 256, 0, stream>>>(agg2, h1b, Wl2, bl2, Wr2, h2b);
    // Layer 3: 32 -> 32, log_softmax -> fp32 d_out
    gather32_kernel<<<gb, 256, 0, stream>>>(h2b, offsets, csr_src, agg3);
    dense_kernel<32, 16, 16, 0, 2><<<db, 256, 0, stream>>>(agg3, h2b, Wl3, bl3, Wr3, d_out);
}